// Round 8
// baseline (420.954 us; speedup 1.0000x reference)
//
#include <hip/hip_runtime.h>

typedef __attribute__((ext_vector_type(8))) short  short8;
typedef __attribute__((ext_vector_type(4))) float  f32x4;
typedef __attribute__((ext_vector_type(4))) ushort us4;
typedef __attribute__((ext_vector_type(4))) uint   u32x4;
typedef __attribute__((ext_vector_type(2))) uint   u32x2;
typedef unsigned long long ull;

__device__ __forceinline__ float bf2f(ushort u) {
    union { uint i; float f; } c; c.i = ((uint)u) << 16; return c.f;
}
__device__ __forceinline__ float bits2f(uint b) {
    union { uint i; float f; } c; c.i = b; return c.f;
}
__device__ __forceinline__ ushort f2bf(float f) {
    union { float f; uint i; } c; c.f = f;
    uint b = c.i + 0x7fffu + ((c.i >> 16) & 1u);   // RNE, no NaN inputs here
    return (ushort)(b >> 16);
}

// ================= CSR build via LDS-binned counting sort ====================
// Contiguous padded CSR (round-7 lesson: CMAX=96 segments inflated the edge
// array 3x; 8 XCD walks made FETCH 103 MB). Node segments are packed back to
// back (each padded to x4 slots for aligned dwordx4 reads), rowptr from a
// per-bucket scan. binD_b packs the FULL bf16 norm dinv_r*w*dinv_c per edge
// (dinv is a 200KB L2-resident table) so GEMM1 stays independent of binning
// and overlaps it via grid-partitioned fused launches (round-6 lesson).
#define NBLK  256     // blocks for histA/binC
#define NBMAX 1024    // max buckets of 64 nodes (N <= 65472)

__device__ __forceinline__
void histA_body(const int* __restrict__ col, int* __restrict__ counts,
                int E, int NB, uint* hist) {
    for (int j = threadIdx.x; j < NB; j += 256) hist[j] = 0u;
    __syncthreads();
    for (int i = blockIdx.x * 256 + threadIdx.x; i < E; i += 256 * NBLK)
        atomicAdd(&hist[((uint)col[i]) >> 6], 1u);
    __syncthreads();
    for (int j = threadIdx.x; j < NB; j += 256)
        counts[j * NBLK + blockIdx.x] = (int)hist[j];
}

__device__ __forceinline__
void binC_body(const int* __restrict__ row, const int* __restrict__ col,
               const float* __restrict__ w,
               const int* __restrict__ counts, const int* __restrict__ bbase,
               ull* __restrict__ recs, int E, int NB, uint* cur) {
    for (int j = threadIdx.x; j < NB; j += 256)
        cur[j] = (uint)(bbase[j] + counts[j * NBLK + blockIdx.x]);
    __syncthreads();
    for (int i = blockIdx.x * 256 + threadIdx.x; i < E; i += 256 * NBLK) {
        int c = col[i], r = row[i];
        float wv = w[i];
        uint w16 = (uint)(wv * 65536.0f);
        if (w16 > 65535u) w16 = 65535u;
        uint pos = atomicAdd(&cur[((uint)c) >> 6], 1u);
        recs[pos] = ((ull)(uint)c << 32) | (ull)((w16 << 16) | (uint)(r & 0xffff));
    }
}

// per bucket: per-node count/wsum -> dinv, padded count, bucket padded total.
__device__ __forceinline__
void binDa_body(const ull* __restrict__ recs, const int* __restrict__ bbase,
                int* __restrict__ cntp, float* __restrict__ dinv,
                int* __restrict__ btotP, int N,
                uint* cnt, uint* ws, uint* red) {
    int b = blockIdx.x, t = threadIdx.x;
    if (t < 64) { cnt[t] = 0u; ws[t] = 0u; }
    __syncthreads();
    int lo = bbase[b], hi = bbase[b + 1];
    for (int i = lo + t; i < hi; i += 256) {
        ull rec = recs[i];
        atomicAdd(&cnt[((uint)(rec >> 32)) & 63u], 1u);
        atomicAdd(&ws[((uint)(rec >> 32)) & 63u], (uint)((rec >> 16) & 0xffffu));
    }
    __syncthreads();
    uint cp = 0;
    if (t < 64) {
        int node = b * 64 + t;
        if (node < N) {
            cp = (cnt[t] + 3u) & ~3u;
            cntp[node] = (int)cp;
            dinv[node] = rsqrtf(1.0f + (float)ws[t] * (1.0f / 65536.0f));
        }
        red[t] = cp;
    }
    __syncthreads();
    if (t < 32) red[t] += red[t + 32];
    __syncthreads();
    if (t < 16) red[t] += red[t + 16];
    __syncthreads();
    if (t < 8) red[t] += red[t + 8];
    __syncthreads();
    if (t < 4) red[t] += red[t + 4];
    __syncthreads();
    if (t == 0) btotP[b] = (int)(red[0] + red[1] + red[2] + red[3]);
}

// per bucket: rowptr = bucket base + local prefix; place edges with packed
// bf16 norm at contiguous positions; zero the x4 pad slots.
__device__ __forceinline__
void binDb_body(const ull* __restrict__ recs, const int* __restrict__ bbase,
                const int* __restrict__ bbaseP, const int* __restrict__ cntp,
                const float* __restrict__ dinv, int* __restrict__ rowptr,
                uint* __restrict__ edgesP, int N,
                uint* arr, uint* curN, uint* rbs) {
    int b = blockIdx.x, t = threadIdx.x;
    int node = b * 64 + t;
    uint cp = 0;
    if (t < 64 && node < N) cp = (uint)cntp[node];
    if (t < 64) arr[t] = cp;
    __syncthreads();
    for (int off = 1; off < 64; off <<= 1) {
        uint x = (t < 64 && t >= off) ? arr[t - off] : 0u;
        __syncthreads();
        if (t < 64) arr[t] += x;
        __syncthreads();
    }
    if (t < 64) {
        uint rb = (uint)bbaseP[b] + arr[t] - cp;
        rbs[t] = rb; curN[t] = rb;
        if (node < N) rowptr[node] = (int)rb;
    }
    __syncthreads();
    int lo = bbase[b], hi = bbase[b + 1];
    for (int i = lo + t; i < hi; i += 256) {
        ull rec = recs[i];
        uint c   = (uint)(rec >> 32);
        uint r   = (uint)rec & 0xffffu;
        uint w16 = ((uint)rec >> 16) & 0xffffu;
        float nv = dinv[r] * ((float)w16 * (1.0f / 65536.0f)) * dinv[c];
        uint slot = atomicAdd(&curN[c & 63u], 1u);
        edgesP[slot] = r | ((uint)f2bf(nv) << 16);
    }
    __syncthreads();
    if (t < 64 && node < N) {
        uint e1 = rbs[t] + cp;
        for (uint j = curN[t]; j < e1; ++j) edgesP[j] = 0u;  // nv=0, r=0 pad
    }
}

// exclusive scan of counts[b][0..255] in place; bucket totals out.
__global__ void k_scanB1(int* __restrict__ counts, int* __restrict__ btot) {
    __shared__ int s[256];
    int b = blockIdx.x, t = threadIdx.x;
    int v = counts[b * NBLK + t];
    s[t] = v; __syncthreads();
    for (int off = 1; off < 256; off <<= 1) {
        int x = (t >= off) ? s[t - off] : 0;
        __syncthreads();
        s[t] += x;
        __syncthreads();
    }
    counts[b * NBLK + t] = s[t] - v;
    if (t == 255) btot[b] = s[255];
}

// exclusive scan of up to 1023 totals -> base[0..NB].
__global__ void k_scanB2(const int* __restrict__ btot, int* __restrict__ bbase, int NB) {
    __shared__ int s[256];
    int t = threadIdx.x;
    int v[4]; int sum = 0;
    #pragma unroll
    for (int j = 0; j < 4; ++j) {
        int i = t * 4 + j;
        v[j] = (i < NB) ? btot[i] : 0;
        sum += v[j];
    }
    s[t] = sum; __syncthreads();
    for (int off = 1; off < 256; off <<= 1) {
        int x = (t >= off) ? s[t - off] : 0;
        __syncthreads();
        s[t] += x;
        __syncthreads();
    }
    int excl = s[t] - sum;
    #pragma unroll
    for (int j = 0; j < 4; ++j) {
        int i = t * 4 + j;
        if (i <= NB) bbase[i] = excl;
        excl += v[j];
    }
}

// ================= weight split + transpose: W[K][N] -> WT{h,l}[N][K] ==========
__device__ __forceinline__
void splitT_body(const float* __restrict__ W, ushort* __restrict__ Th,
                 ushort* __restrict__ Tl, int K, int N, int i) {
    if (i < K * N) {
        int k = i / N, n = i - k * N;
        float v = W[i];
        ushort hi = f2bf(v);
        ushort lo = f2bf(v - bf2f(hi));
        Th[(size_t)n * K + k] = hi;
        Tl[(size_t)n * K + k] = lo;
    }
}

// ================= MFMA GEMM core =============================================
// Tile 128x128, BK=32, 256 thr = 4 waves (2x2), wave = 64x64 = 4x4 MFMA tiles.
// 3-product split precision: Ah*Bh + Ah*Bl + Al*Bh.
#define LDA 40   // padded LDS row stride (bf16 elems); 80 B = 5*16 keeps 16B align

__device__ __forceinline__
void gemm3_body(const float* __restrict__ A, const ushort* __restrict__ BTh,
                const ushort* __restrict__ BTl, ushort* __restrict__ Cpan,
                int M, int Nc, int K, int bm, int bn,
                ushort (*As)[128][LDA], ushort (*Bs)[128][LDA]) {
    const int t    = threadIdx.x;
    const int lane = t & 63;
    const int wid  = t >> 6;
    const int wm   = wid >> 1;
    const int wn   = wid & 1;
    const int ml   = lane & 15;
    const int kq   = lane >> 4;

    f32x4 acc[4][4];
    #pragma unroll
    for (int mt = 0; mt < 4; ++mt)
        #pragma unroll
        for (int nt = 0; nt < 4; ++nt) acc[mt][nt] = (f32x4){0.f, 0.f, 0.f, 0.f};

    for (int k0 = 0; k0 < K; k0 += 32) {
        #pragma unroll
        for (int it = 0; it < 4; ++it) {
            int idx = (t + it * 256) * 4;
            int r  = idx >> 5;
            int kk = idx & 31;
            int grow = bm + r;
            f32x4 v = (f32x4){0.f, 0.f, 0.f, 0.f};
            if (grow < M) v = *(const f32x4*)&A[(size_t)grow * K + k0 + kk];
            us4 hi, lo;
            #pragma unroll
            for (int j = 0; j < 4; ++j) {
                ushort h = f2bf(v[j]);
                hi[j] = h;
                lo[j] = f2bf(v[j] - bf2f(h));
            }
            *(us4*)&As[0][r][kk] = hi;
            *(us4*)&As[1][r][kk] = lo;
        }
        #pragma unroll
        for (int it = 0; it < 2; ++it) {
            int idx = (t + it * 256) * 8;
            int n  = idx >> 5;
            int kk = idx & 31;
            u32x4 vh = *(const u32x4*)&BTh[(size_t)(bn + n) * K + k0 + kk];
            *(u32x4*)&Bs[0][n][kk] = vh;
            u32x4 vl = *(const u32x4*)&BTl[(size_t)(bn + n) * K + k0 + kk];
            *(u32x4*)&Bs[1][n][kk] = vl;
        }
        __syncthreads();

        short8 a[4][2], b[4][2];
        #pragma unroll
        for (int mt = 0; mt < 4; ++mt) {
            a[mt][0] = *(const short8*)&As[0][wm * 64 + mt * 16 + ml][kq * 8];
            a[mt][1] = *(const short8*)&As[1][wm * 64 + mt * 16 + ml][kq * 8];
        }
        #pragma unroll
        for (int nt = 0; nt < 4; ++nt) {
            b[nt][0] = *(const short8*)&Bs[0][wn * 64 + nt * 16 + ml][kq * 8];
            b[nt][1] = *(const short8*)&Bs[1][wn * 64 + nt * 16 + ml][kq * 8];
        }
        #pragma unroll
        for (int mt = 0; mt < 4; ++mt)
            #pragma unroll
            for (int nt = 0; nt < 4; ++nt) {
                acc[mt][nt] = __builtin_amdgcn_mfma_f32_16x16x32_bf16(a[mt][0], b[nt][0], acc[mt][nt], 0, 0, 0);
                acc[mt][nt] = __builtin_amdgcn_mfma_f32_16x16x32_bf16(a[mt][0], b[nt][1], acc[mt][nt], 0, 0, 0);
                acc[mt][nt] = __builtin_amdgcn_mfma_f32_16x16x32_bf16(a[mt][1], b[nt][0], acc[mt][nt], 0, 0, 0);
            }
        __syncthreads();
    }

    #pragma unroll
    for (int mt = 0; mt < 4; ++mt) {
        int rbase = bm + wm * 64 + mt * 16 + kq * 4;
        #pragma unroll
        for (int nt = 0; nt < 4; ++nt) {
            int colg = bn + wn * 64 + nt * 16 + ml;
            size_t pbase = (size_t)(colg >> 5) * M * 32 + (colg & 31);
            #pragma unroll
            for (int r = 0; r < 4; ++r) {
                int rr = rbase + r;
                if (rr < M) Cpan[pbase + (size_t)rr * 32] = f2bf(acc[mt][nt][r]);
            }
        }
    }
}

__global__ __launch_bounds__(256)
void k_gemm3(const float* __restrict__ A, const ushort* __restrict__ BTh,
             const ushort* __restrict__ BTl, ushort* __restrict__ Cpan,
             int M, int Nc, int K) {
    __shared__ __align__(16) ushort As[2][128][LDA];
    __shared__ __align__(16) ushort Bs[2][128][LDA];
    gemm3_body(A, BTh, BTl, Cpan, M, Nc, K, blockIdx.y * 128, blockIdx.x * 128, As, Bs);
}

// ================= fused launches (binning || GEMM1 tiles) ===================
__global__ __launch_bounds__(256)
void k_fusedA(const int* __restrict__ col, int* __restrict__ counts, int E, int NB,
              const float* __restrict__ W1, ushort* __restrict__ WT1h, ushort* __restrict__ WT1l,
              int Fin, int H,
              const float* __restrict__ W2, ushort* __restrict__ WT2h, ushort* __restrict__ WT2l,
              int Fout, int sp1) {
    __shared__ uint hist[NBMAX];
    int bid = (int)blockIdx.x;
    if (bid < NBLK) { histA_body(col, counts, E, NB, hist); return; }
    if (bid < NBLK + sp1) { splitT_body(W1, WT1h, WT1l, Fin, H, (bid - NBLK) * 256 + (int)threadIdx.x); return; }
    splitT_body(W2, WT2h, WT2l, H, Fout, (bid - NBLK - sp1) * 256 + (int)threadIdx.x);
}

__global__ __launch_bounds__(256)
void k_fusedB1(const int* __restrict__ row, const int* __restrict__ col,
               const float* __restrict__ w, const int* __restrict__ counts,
               const int* __restrict__ bbase, ull* __restrict__ recs, int E, int NB,
               const float* __restrict__ A, const ushort* __restrict__ BTh,
               const ushort* __restrict__ BTl, ushort* __restrict__ Cpan,
               int M, int Nc, int K, int t0) {
    __shared__ __align__(16) ushort As[2][128][LDA];
    __shared__ __align__(16) ushort Bs[2][128][LDA];
    int bid = (int)blockIdx.x;
    if (bid < NBLK) { binC_body(row, col, w, counts, bbase, recs, E, NB, (uint*)&As[0][0][0]); return; }
    int tile = t0 + bid - NBLK;
    int nbn = Nc >> 7;
    gemm3_body(A, BTh, BTl, Cpan, M, Nc, K, (tile / nbn) * 128, (tile % nbn) * 128, As, Bs);
}

__global__ __launch_bounds__(256)
void k_fusedB2(const ull* __restrict__ recs, const int* __restrict__ bbase,
               int* __restrict__ cntp, float* __restrict__ dinv, int* __restrict__ btotP,
               int N, int NB,
               const float* __restrict__ A, const ushort* __restrict__ BTh,
               const ushort* __restrict__ BTl, ushort* __restrict__ Cpan,
               int M, int Nc, int K, int t0) {
    __shared__ __align__(16) ushort As[2][128][LDA];
    __shared__ __align__(16) ushort Bs[2][128][LDA];
    int bid = (int)blockIdx.x;
    if (bid < NB) {
        uint* l = (uint*)&As[0][0][0];
        binDa_body(recs, bbase, cntp, dinv, btotP, N, l, l + 64, l + 128);
        return;
    }
    int tile = t0 + bid - NB;
    int nbn = Nc >> 7;
    gemm3_body(A, BTh, BTl, Cpan, M, Nc, K, (tile / nbn) * 128, (tile % nbn) * 128, As, Bs);
}

__global__ __launch_bounds__(256)
void k_fusedB3(const ull* __restrict__ recs, const int* __restrict__ bbase,
               const int* __restrict__ bbaseP, const int* __restrict__ cntp,
               const float* __restrict__ dinv, int* __restrict__ rowptr,
               uint* __restrict__ edgesP, int N, int NB,
               const float* __restrict__ A, const ushort* __restrict__ BTh,
               const ushort* __restrict__ BTl, ushort* __restrict__ Cpan,
               int M, int Nc, int K, int t0) {
    __shared__ __align__(16) ushort As[2][128][LDA];
    __shared__ __align__(16) ushort Bs[2][128][LDA];
    int bid = (int)blockIdx.x;
    if (bid < NB) {
        uint* l = (uint*)&As[0][0][0];
        binDb_body(recs, bbase, bbaseP, cntp, dinv, rowptr, edgesP, N, l, l + 64, l + 128);
        return;
    }
    int tile = t0 + bid - NB;
    int nbn = Nc >> 7;
    gemm3_body(A, BTh, BTl, Cpan, M, Nc, K, (tile / nbn) * 128, (tile % nbn) * 128, As, Bs);
}

// ================= panel CSR aggregation, butterfly-free =====================
// Panel-per-block (p = bid % npan): consecutive blocks round-robin XCDs so each
// XCD's L2 holds ONE 3.2 MB panel -> gathers stay L2-resident.
// Lane layout: g=lane>>3 (8 nodes per wave, serial edges), c=lane&7 (4 feats
// per lane, one dwordx2 gather). No cross-lane reduction. Edge packets 4 at a
// time from one 16B-aligned dwordx4 (contiguous CSR, segments padded to x4).
#define NODES_PER_BLK 32

template <bool RELU>
__device__ __forceinline__
void aggr_body(const int* __restrict__ rowptr, const int* __restrict__ cntp,
               const uint* __restrict__ edges,
               const ushort* __restrict__ hpan, const float* __restrict__ dinv,
               const float* __restrict__ bias, float* __restrict__ out,
               int F, int npan, int N) {
    const int bid  = blockIdx.x;
    const int p    = bid % npan;
    const int wave = threadIdx.x >> 6;
    const int lane = threadIdx.x & 63;
    const int g    = lane >> 3;        // node within wave
    const int c    = lane & 7;         // feature quad within panel
    const int node = (bid / npan) * NODES_PER_BLK + wave * 8 + g;
    const int fbase = p * 32 + c * 4;

    const ushort* hp = hpan + (size_t)p * N * 32 + c * 4;   // + r*32 per gather

    int beg = 0, end = 0;
    if (node < N) { beg = rowptr[node]; end = beg + cntp[node]; }

    float a0 = 0.f, a1 = 0.f, a2 = 0.f, a3 = 0.f;
    int e = beg;
    u32x4 pk4 = (u32x4){0u, 0u, 0u, 0u};
    if (e < end) pk4 = *(const u32x4*)&edges[e];
    while (__any(e < end)) {
        u32x4 cur = pk4;
        int e2 = e + 4;
        if (e2 < end) pk4 = *(const u32x4*)&edges[e2];   // prefetch next packet
        if (e < end) {
            #pragma unroll
            for (int j = 0; j < 4; ++j) {
                uint pk = cur[j];
                float nv = bits2f(pk & 0xffff0000u);
                int r = (int)(pk & 0xffffu);
                u32x2 hv = *(const u32x2*)(hp + (size_t)r * 32);
                a0 += nv * bits2f(hv[0] << 16);
                a1 += nv * bits2f(hv[0] & 0xffff0000u);
                a2 += nv * bits2f(hv[1] << 16);
                a3 += nv * bits2f(hv[1] & 0xffff0000u);
            }
        }
        e = e2;
    }

    if (node < N) {
        float di = dinv[node];
        float d2 = di * di;
        u32x2 hs = *(const u32x2*)(hp + (size_t)node * 32);
        f32x4 bv = *(const f32x4*)&bias[fbase];
        f32x4 v;
        v[0] = a0 + d2 * bits2f(hs[0] << 16)         + bv[0];
        v[1] = a1 + d2 * bits2f(hs[0] & 0xffff0000u) + bv[1];
        v[2] = a2 + d2 * bits2f(hs[1] << 16)         + bv[2];
        v[3] = a3 + d2 * bits2f(hs[1] & 0xffff0000u) + bv[3];
        if (RELU) {
            v[0] = fmaxf(v[0], 0.f); v[1] = fmaxf(v[1], 0.f);
            v[2] = fmaxf(v[2], 0.f); v[3] = fmaxf(v[3], 0.f);
        }
        *(f32x4*)&out[(size_t)node * F + fbase] = v;
    }
}

__global__ __launch_bounds__(256)
void k_aggr1(const int* __restrict__ rowptr, const int* __restrict__ cntp,
             const uint* __restrict__ edges, const ushort* __restrict__ hpan,
             const float* __restrict__ dinv, const float* __restrict__ bias,
             float* __restrict__ out, int F, int npan, int N) {
    aggr_body<true>(rowptr, cntp, edges, hpan, dinv, bias, out, F, npan, N);
}

__global__ __launch_bounds__(256)
void k_aggr2(const int* __restrict__ rowptr, const int* __restrict__ cntp,
             const uint* __restrict__ edges, const ushort* __restrict__ hpan,
             const float* __restrict__ dinv, const float* __restrict__ bias,
             float* __restrict__ out, int F, int npan, int N) {
    aggr_body<false>(rowptr, cntp, edges, hpan, dinv, bias, out, F, npan, N);
}

// ================= launcher =================

static inline char* bump(char*& p, size_t bytes) {
    char* r = p;
    p += (bytes + 255) & ~(size_t)255;
    return r;
}

extern "C" void kernel_launch(void* const* d_in, const int* in_sizes, int n_in,
                              void* d_out, int out_size, void* d_ws, size_t ws_size,
                              hipStream_t stream) {
    const float* x  = (const float*)d_in[0];
    const int*   ei = (const int*)d_in[1];
    const float* ew = (const float*)d_in[2];
    const float* W1 = (const float*)d_in[3];
    const float* b1 = (const float*)d_in[4];
    const float* W2 = (const float*)d_in[5];
    const float* b2 = (const float*)d_in[6];
    float* out = (float*)d_out;

    const int E    = in_sizes[2];
    const int H    = in_sizes[4];       // 256
    const int Fout = in_sizes[6];       // 128
    const int Fin  = in_sizes[3] / H;   // 256
    const int N    = in_sizes[0] / Fin; // 50000 (fits ushort)
    const int NB   = (N + 63) >> 6;     // buckets of 64 nodes (<= 1023)

    const int* row = ei;
    const int* col = ei + E;

    char* p = (char*)d_ws;
    float*  dinv   = (float*)bump(p, (size_t)N * 4);
    int*    cntp   = (int*)bump(p, (size_t)N * 4);
    int*    rowptr = (int*)bump(p, (size_t)N * 4);
    uint*   edgesP = (uint*)bump(p, ((size_t)E + 4 * N + 256) * 4);
    int*    counts = (int*)bump(p, (size_t)NBMAX * NBLK * 4);
    int*    btot   = (int*)bump(p, (size_t)NBMAX * 4);
    int*    bbase  = (int*)bump(p, (size_t)(NBMAX + 1) * 4);
    int*    btotP  = (int*)bump(p, (size_t)NBMAX * 4);
    int*    bbaseP = (int*)bump(p, (size_t)(NBMAX + 1) * 4);
    ushort* WT1h   = (ushort*)bump(p, (size_t)Fin * H * 2);
    ushort* WT1l   = (ushort*)bump(p, (size_t)Fin * H * 2);
    ushort* WT2h   = (ushort*)bump(p, (size_t)H * Fout * 2);
    ushort* WT2l   = (ushort*)bump(p, (size_t)H * Fout * 2);
    ushort* h1     = (ushort*)bump(p, (size_t)N * H * 2);     // panel-major bf16
    float*  a1     = (float*)bump(p, (size_t)N * H * 4);      // row-major fp32
    ushort* h2     = (ushort*)bump(p, (size_t)N * Fout * 2);  // panel-major bf16

    // recs overlays a1: consumed by binD_a/b before a1 is first written.
    ull* recs = (ull*)a1;

    const int sp1 = (Fin * H + 255) / 256;      // 256
    const int sp2 = (H * Fout + 255) / 256;     // 128
    const int gb1 = (H / 128) * ((N + 127) / 128);   // GEMM1 tiles (782)
    int T1 = gb1 < 280 ? gb1 : 280;
    int T2 = gb1 < 480 ? gb1 : 480;
    if (T2 < T1) T2 = T1;

    // stage A: edge histogram || weight split/transpose
    k_fusedA<<<NBLK + sp1 + sp2, 256, 0, stream>>>(col, counts, E, NB,
                                                   W1, WT1h, WT1l, Fin, H,
                                                   W2, WT2h, WT2l, Fout, sp1);
    k_scanB1<<<NB, 256, 0, stream>>>(counts, btot);
    k_scanB2<<<1, 256, 0, stream>>>(btot, bbase, NB);
    // stage B: bucket-sort || GEMM1 tiles [0,T1)
    k_fusedB1<<<NBLK + T1, 256, 0, stream>>>(row, col, ew, counts, bbase, recs, E, NB,
                                             x, WT1h, WT1l, h1, N, H, Fin, 0);
    // stage C: per-node counts/dinv || GEMM1 tiles [T1,T2)
    k_fusedB2<<<NB + (T2 - T1), 256, 0, stream>>>(recs, bbase, cntp, dinv, btotP, N, NB,
                                                  x, WT1h, WT1l, h1, N, H, Fin, T1);
    k_scanB2<<<1, 256, 0, stream>>>(btotP, bbaseP, NB);
    // stage D: CSR emission (packed bf16 norm) || GEMM1 tiles [T2,gb1)
    k_fusedB3<<<NB + (gb1 - T2), 256, 0, stream>>>(recs, bbase, bbaseP, cntp, dinv,
                                                   rowptr, edgesP, N, NB,
                                                   x, WT1h, WT1l, h1, N, H, Fin, T2);

    const int chunks = (N + NODES_PER_BLK - 1) / NODES_PER_BLK;

    // layer 1 aggregation
    k_aggr1<<<chunks * (H / 32), 256, 0, stream>>>(rowptr, cntp, edgesP, h1, dinv, b1, a1, H, H / 32, N);

    // layer 2
    k_gemm3<<<dim3(Fout / 128, (N + 127) / 128), 256, 0, stream>>>(a1, WT2h, WT2l, h2, N, Fout, H);
    k_aggr2<<<chunks * (Fout / 32), 256, 0, stream>>>(rowptr, cntp, edgesP, h2, dinv, b2, out, Fout, Fout / 32, N);
}

// Round 9
// 417.515 us; speedup vs baseline: 1.0082x; 1.0082x over previous
//
#include <hip/hip_runtime.h>

typedef __attribute__((ext_vector_type(8))) short  short8;
typedef __attribute__((ext_vector_type(4))) float  f32x4;
typedef __attribute__((ext_vector_type(4))) ushort us4;
typedef __attribute__((ext_vector_type(4))) uint   u32x4;
typedef __attribute__((ext_vector_type(2))) uint   u32x2;
typedef unsigned long long ull;

__device__ __forceinline__ float bf2f(ushort u) {
    union { uint i; float f; } c; c.i = ((uint)u) << 16; return c.f;
}
__device__ __forceinline__ float bits2f(uint b) {
    union { uint i; float f; } c; c.i = b; return c.f;
}
__device__ __forceinline__ ushort f2bf(float f) {
    union { float f; uint i; } c; c.f = f;
    uint b = c.i + 0x7fffu + ((c.i >> 16) & 1u);   // RNE, no NaN inputs here
    return (ushort)(b >> 16);
}

// ================= CSR build via LDS-binned counting sort ====================
// Contiguous padded CSR. Node segments packed back to back (each padded to x4
// slots for aligned dwordx4 reads), rowptr from a per-bucket scan. binD_b packs
// the FULL bf16 norm dinv_r*w*dinv_c per edge (dinv is a 200KB L2-resident
// table) so GEMM1 stays independent of binning and overlaps it via
// grid-partitioned fused launches.
#define NBLK  256     // blocks for histA/binC
#define NBMAX 1024    // max buckets of 64 nodes (N <= 65472)

__device__ __forceinline__
void histA_body(const int* __restrict__ col, int* __restrict__ counts,
                int E, int NB, uint* hist) {
    for (int j = threadIdx.x; j < NB; j += 256) hist[j] = 0u;
    __syncthreads();
    for (int i = blockIdx.x * 256 + threadIdx.x; i < E; i += 256 * NBLK)
        atomicAdd(&hist[((uint)col[i]) >> 6], 1u);
    __syncthreads();
    for (int j = threadIdx.x; j < NB; j += 256)
        counts[j * NBLK + blockIdx.x] = (int)hist[j];
}

__device__ __forceinline__
void binC_body(const int* __restrict__ row, const int* __restrict__ col,
               const float* __restrict__ w,
               const int* __restrict__ counts, const int* __restrict__ bbase,
               ull* __restrict__ recs, int E, int NB, uint* cur) {
    for (int j = threadIdx.x; j < NB; j += 256)
        cur[j] = (uint)(bbase[j] + counts[j * NBLK + blockIdx.x]);
    __syncthreads();
    for (int i = blockIdx.x * 256 + threadIdx.x; i < E; i += 256 * NBLK) {
        int c = col[i], r = row[i];
        float wv = w[i];
        uint w16 = (uint)(wv * 65536.0f);
        if (w16 > 65535u) w16 = 65535u;
        uint pos = atomicAdd(&cur[((uint)c) >> 6], 1u);
        recs[pos] = ((ull)(uint)c << 32) | (ull)((w16 << 16) | (uint)(r & 0xffff));
    }
}

// per bucket: per-node count/wsum -> dinv, padded count, bucket padded total.
__device__ __forceinline__
void binDa_body(const ull* __restrict__ recs, const int* __restrict__ bbase,
                int* __restrict__ cntp, float* __restrict__ dinv,
                int* __restrict__ btotP, int N,
                uint* cnt, uint* ws, uint* red) {
    int b = blockIdx.x, t = threadIdx.x;
    if (t < 64) { cnt[t] = 0u; ws[t] = 0u; }
    __syncthreads();
    int lo = bbase[b], hi = bbase[b + 1];
    for (int i = lo + t; i < hi; i += 256) {
        ull rec = recs[i];
        atomicAdd(&cnt[((uint)(rec >> 32)) & 63u], 1u);
        atomicAdd(&ws[((uint)(rec >> 32)) & 63u], (uint)((rec >> 16) & 0xffffu));
    }
    __syncthreads();
    uint cp = 0;
    if (t < 64) {
        int node = b * 64 + t;
        if (node < N) {
            cp = (cnt[t] + 3u) & ~3u;
            cntp[node] = (int)cp;
            dinv[node] = rsqrtf(1.0f + (float)ws[t] * (1.0f / 65536.0f));
        }
        red[t] = cp;
    }
    __syncthreads();
    if (t < 32) red[t] += red[t + 32];
    __syncthreads();
    if (t < 16) red[t] += red[t + 16];
    __syncthreads();
    if (t < 8) red[t] += red[t + 8];
    __syncthreads();
    if (t < 4) red[t] += red[t + 4];
    __syncthreads();
    if (t == 0) btotP[b] = (int)(red[0] + red[1] + red[2] + red[3]);
}

// per bucket: rowptr = bucket base + local prefix; place edges with packed
// bf16 norm at contiguous positions; zero the x4 pad slots.
__device__ __forceinline__
void binDb_body(const ull* __restrict__ recs, const int* __restrict__ bbase,
                const int* __restrict__ bbaseP, const int* __restrict__ cntp,
                const float* __restrict__ dinv, int* __restrict__ rowptr,
                uint* __restrict__ edgesP, int N,
                uint* arr, uint* curN, uint* rbs) {
    int b = blockIdx.x, t = threadIdx.x;
    int node = b * 64 + t;
    uint cp = 0;
    if (t < 64 && node < N) cp = (uint)cntp[node];
    if (t < 64) arr[t] = cp;
    __syncthreads();
    for (int off = 1; off < 64; off <<= 1) {
        uint x = (t < 64 && t >= off) ? arr[t - off] : 0u;
        __syncthreads();
        if (t < 64) arr[t] += x;
        __syncthreads();
    }
    if (t < 64) {
        uint rb = (uint)bbaseP[b] + arr[t] - cp;
        rbs[t] = rb; curN[t] = rb;
        if (node < N) rowptr[node] = (int)rb;
    }
    __syncthreads();
    int lo = bbase[b], hi = bbase[b + 1];
    for (int i = lo + t; i < hi; i += 256) {
        ull rec = recs[i];
        uint c   = (uint)(rec >> 32);
        uint r   = (uint)rec & 0xffffu;
        uint w16 = ((uint)rec >> 16) & 0xffffu;
        float nv = dinv[r] * ((float)w16 * (1.0f / 65536.0f)) * dinv[c];
        uint slot = atomicAdd(&curN[c & 63u], 1u);
        edgesP[slot] = r | ((uint)f2bf(nv) << 16);
    }
    __syncthreads();
    if (t < 64 && node < N) {
        uint e1 = rbs[t] + cp;
        for (uint j = curN[t]; j < e1; ++j) edgesP[j] = 0u;  // nv=0, r=0 pad
    }
}

// exclusive scan of counts[b][0..255] in place; bucket totals out.
__global__ void k_scanB1(int* __restrict__ counts, int* __restrict__ btot) {
    __shared__ int s[256];
    int b = blockIdx.x, t = threadIdx.x;
    int v = counts[b * NBLK + t];
    s[t] = v; __syncthreads();
    for (int off = 1; off < 256; off <<= 1) {
        int x = (t >= off) ? s[t - off] : 0;
        __syncthreads();
        s[t] += x;
        __syncthreads();
    }
    counts[b * NBLK + t] = s[t] - v;
    if (t == 255) btot[b] = s[255];
}

// exclusive scan of up to 1023 totals -> base[0..NB].
__global__ void k_scanB2(const int* __restrict__ btot, int* __restrict__ bbase, int NB) {
    __shared__ int s[256];
    int t = threadIdx.x;
    int v[4]; int sum = 0;
    #pragma unroll
    for (int j = 0; j < 4; ++j) {
        int i = t * 4 + j;
        v[j] = (i < NB) ? btot[i] : 0;
        sum += v[j];
    }
    s[t] = sum; __syncthreads();
    for (int off = 1; off < 256; off <<= 1) {
        int x = (t >= off) ? s[t - off] : 0;
        __syncthreads();
        s[t] += x;
        __syncthreads();
    }
    int excl = s[t] - sum;
    #pragma unroll
    for (int j = 0; j < 4; ++j) {
        int i = t * 4 + j;
        if (i <= NB) bbase[i] = excl;
        excl += v[j];
    }
}

// ================= weight split + transpose: W[K][N] -> WT{h,l}[N][K] ==========
__device__ __forceinline__
void splitT_body(const float* __restrict__ W, ushort* __restrict__ Th,
                 ushort* __restrict__ Tl, int K, int N, int i) {
    if (i < K * N) {
        int k = i / N, n = i - k * N;
        float v = W[i];
        ushort hi = f2bf(v);
        ushort lo = f2bf(v - bf2f(hi));
        Th[(size_t)n * K + k] = hi;
        Tl[(size_t)n * K + k] = lo;
    }
}

// ================= MFMA GEMM core =============================================
// Tile 128x128, BK=32, 256 thr = 4 waves (2x2), wave = 64x64 = 4x4 MFMA tiles.
// 3-product split precision: Ah*Bh + Ah*Bl + Al*Bh.
#define LDA 40   // padded LDS row stride (bf16 elems); 80 B = 5*16 keeps 16B align

__device__ __forceinline__
void gemm3_body(const float* __restrict__ A, const ushort* __restrict__ BTh,
                const ushort* __restrict__ BTl, ushort* __restrict__ Cpan,
                int M, int Nc, int K, int bm, int bn,
                ushort (*As)[128][LDA], ushort (*Bs)[128][LDA]) {
    const int t    = threadIdx.x;
    const int lane = t & 63;
    const int wid  = t >> 6;
    const int wm   = wid >> 1;
    const int wn   = wid & 1;
    const int ml   = lane & 15;
    const int kq   = lane >> 4;

    f32x4 acc[4][4];
    #pragma unroll
    for (int mt = 0; mt < 4; ++mt)
        #pragma unroll
        for (int nt = 0; nt < 4; ++nt) acc[mt][nt] = (f32x4){0.f, 0.f, 0.f, 0.f};

    for (int k0 = 0; k0 < K; k0 += 32) {
        #pragma unroll
        for (int it = 0; it < 4; ++it) {
            int idx = (t + it * 256) * 4;
            int r  = idx >> 5;
            int kk = idx & 31;
            int grow = bm + r;
            f32x4 v = (f32x4){0.f, 0.f, 0.f, 0.f};
            if (grow < M) v = *(const f32x4*)&A[(size_t)grow * K + k0 + kk];
            us4 hi, lo;
            #pragma unroll
            for (int j = 0; j < 4; ++j) {
                ushort h = f2bf(v[j]);
                hi[j] = h;
                lo[j] = f2bf(v[j] - bf2f(h));
            }
            *(us4*)&As[0][r][kk] = hi;
            *(us4*)&As[1][r][kk] = lo;
        }
        #pragma unroll
        for (int it = 0; it < 2; ++it) {
            int idx = (t + it * 256) * 8;
            int n  = idx >> 5;
            int kk = idx & 31;
            u32x4 vh = *(const u32x4*)&BTh[(size_t)(bn + n) * K + k0 + kk];
            *(u32x4*)&Bs[0][n][kk] = vh;
            u32x4 vl = *(const u32x4*)&BTl[(size_t)(bn + n) * K + k0 + kk];
            *(u32x4*)&Bs[1][n][kk] = vl;
        }
        __syncthreads();

        short8 a[4][2], b[4][2];
        #pragma unroll
        for (int mt = 0; mt < 4; ++mt) {
            a[mt][0] = *(const short8*)&As[0][wm * 64 + mt * 16 + ml][kq * 8];
            a[mt][1] = *(const short8*)&As[1][wm * 64 + mt * 16 + ml][kq * 8];
        }
        #pragma unroll
        for (int nt = 0; nt < 4; ++nt) {
            b[nt][0] = *(const short8*)&Bs[0][wn * 64 + nt * 16 + ml][kq * 8];
            b[nt][1] = *(const short8*)&Bs[1][wn * 64 + nt * 16 + ml][kq * 8];
        }
        #pragma unroll
        for (int mt = 0; mt < 4; ++mt)
            #pragma unroll
            for (int nt = 0; nt < 4; ++nt) {
                acc[mt][nt] = __builtin_amdgcn_mfma_f32_16x16x32_bf16(a[mt][0], b[nt][0], acc[mt][nt], 0, 0, 0);
                acc[mt][nt] = __builtin_amdgcn_mfma_f32_16x16x32_bf16(a[mt][0], b[nt][1], acc[mt][nt], 0, 0, 0);
                acc[mt][nt] = __builtin_amdgcn_mfma_f32_16x16x32_bf16(a[mt][1], b[nt][0], acc[mt][nt], 0, 0, 0);
            }
        __syncthreads();
    }

    #pragma unroll
    for (int mt = 0; mt < 4; ++mt) {
        int rbase = bm + wm * 64 + mt * 16 + kq * 4;
        #pragma unroll
        for (int nt = 0; nt < 4; ++nt) {
            int colg = bn + wn * 64 + nt * 16 + ml;
            size_t pbase = (size_t)(colg >> 5) * M * 32 + (colg & 31);
            #pragma unroll
            for (int r = 0; r < 4; ++r) {
                int rr = rbase + r;
                if (rr < M) Cpan[pbase + (size_t)rr * 32] = f2bf(acc[mt][nt][r]);
            }
        }
    }
}

__global__ __launch_bounds__(256)
void k_gemm3(const float* __restrict__ A, const ushort* __restrict__ BTh,
             const ushort* __restrict__ BTl, ushort* __restrict__ Cpan,
             int M, int Nc, int K) {
    __shared__ __align__(16) ushort As[2][128][LDA];
    __shared__ __align__(16) ushort Bs[2][128][LDA];
    gemm3_body(A, BTh, BTl, Cpan, M, Nc, K, blockIdx.y * 128, blockIdx.x * 128, As, Bs);
}

// ================= fused launches (binning || GEMM1 tiles) ===================
__global__ __launch_bounds__(256)
void k_fusedA(const int* __restrict__ col, int* __restrict__ counts, int E, int NB,
              const float* __restrict__ W1, ushort* __restrict__ WT1h, ushort* __restrict__ WT1l,
              int Fin, int H,
              const float* __restrict__ W2, ushort* __restrict__ WT2h, ushort* __restrict__ WT2l,
              int Fout, int sp1) {
    __shared__ uint hist[NBMAX];
    int bid = (int)blockIdx.x;
    if (bid < NBLK) { histA_body(col, counts, E, NB, hist); return; }
    if (bid < NBLK + sp1) { splitT_body(W1, WT1h, WT1l, Fin, H, (bid - NBLK) * 256 + (int)threadIdx.x); return; }
    splitT_body(W2, WT2h, WT2l, H, Fout, (bid - NBLK - sp1) * 256 + (int)threadIdx.x);
}

__global__ __launch_bounds__(256)
void k_fusedB1(const int* __restrict__ row, const int* __restrict__ col,
               const float* __restrict__ w, const int* __restrict__ counts,
               const int* __restrict__ bbase, ull* __restrict__ recs, int E, int NB,
               const float* __restrict__ A, const ushort* __restrict__ BTh,
               const ushort* __restrict__ BTl, ushort* __restrict__ Cpan,
               int M, int Nc, int K, int t0) {
    __shared__ __align__(16) ushort As[2][128][LDA];
    __shared__ __align__(16) ushort Bs[2][128][LDA];
    int bid = (int)blockIdx.x;
    if (bid < NBLK) { binC_body(row, col, w, counts, bbase, recs, E, NB, (uint*)&As[0][0][0]); return; }
    int tile = t0 + bid - NBLK;
    int nbn = Nc >> 7;
    gemm3_body(A, BTh, BTl, Cpan, M, Nc, K, (tile / nbn) * 128, (tile % nbn) * 128, As, Bs);
}

__global__ __launch_bounds__(256)
void k_fusedB2(const ull* __restrict__ recs, const int* __restrict__ bbase,
               int* __restrict__ cntp, float* __restrict__ dinv, int* __restrict__ btotP,
               int N, int NB,
               const float* __restrict__ A, const ushort* __restrict__ BTh,
               const ushort* __restrict__ BTl, ushort* __restrict__ Cpan,
               int M, int Nc, int K, int t0) {
    __shared__ __align__(16) ushort As[2][128][LDA];
    __shared__ __align__(16) ushort Bs[2][128][LDA];
    int bid = (int)blockIdx.x;
    if (bid < NB) {
        uint* l = (uint*)&As[0][0][0];
        binDa_body(recs, bbase, cntp, dinv, btotP, N, l, l + 64, l + 128);
        return;
    }
    int tile = t0 + bid - NB;
    int nbn = Nc >> 7;
    gemm3_body(A, BTh, BTl, Cpan, M, Nc, K, (tile / nbn) * 128, (tile % nbn) * 128, As, Bs);
}

__global__ __launch_bounds__(256)
void k_fusedB3(const ull* __restrict__ recs, const int* __restrict__ bbase,
               const int* __restrict__ bbaseP, const int* __restrict__ cntp,
               const float* __restrict__ dinv, int* __restrict__ rowptr,
               uint* __restrict__ edgesP, int N, int NB,
               const float* __restrict__ A, const ushort* __restrict__ BTh,
               const ushort* __restrict__ BTl, ushort* __restrict__ Cpan,
               int M, int Nc, int K, int t0) {
    __shared__ __align__(16) ushort As[2][128][LDA];
    __shared__ __align__(16) ushort Bs[2][128][LDA];
    int bid = (int)blockIdx.x;
    if (bid < NB) {
        uint* l = (uint*)&As[0][0][0];
        binDb_body(recs, bbase, bbaseP, cntp, dinv, rowptr, edgesP, N, l, l + 64, l + 128);
        return;
    }
    int tile = t0 + bid - NB;
    int nbn = Nc >> 7;
    gemm3_body(A, BTh, BTl, Cpan, M, Nc, K, (tile / nbn) * 128, (tile % nbn) * 128, As, Bs);
}

// ================= panel CSR aggregation, butterfly-free =====================
// Panel-per-block (p = bid % npan): consecutive blocks round-robin XCDs so each
// XCD's L2 holds ONE 3.2 MB panel -> gathers stay L2-resident.
// Round-8 lesson: aggr is issue-bound (VALUBusy 50%, HBM 17%), so lanes were
// rebalanced from 8 nodes x 8 lanes x 4 feats (8B gather) to 16 nodes x 4
// lanes x 8 feats (16B dwordx4 gather): ~2.6 VALU/feature vs 3.25, and each
// wave-level packet-load/gather/loop iteration now serves 16 nodes, halving
// total wave-iterations. No cross-lane reduction. Edge packets 4 at a time
// from one 16B-aligned dwordx4 (contiguous CSR, segments padded to x4).
#define NPB 64   // nodes per block: 4 waves x 16 nodes

template <bool RELU>
__device__ __forceinline__
void aggr_body(const int* __restrict__ rowptr, const int* __restrict__ cntp,
               const uint* __restrict__ edges,
               const ushort* __restrict__ hpan, const float* __restrict__ dinv,
               const float* __restrict__ bias, float* __restrict__ out,
               int F, int npan, int N) {
    const int bid  = blockIdx.x;
    const int p    = bid % npan;
    const int wave = threadIdx.x >> 6;
    const int lane = threadIdx.x & 63;
    const int g    = lane >> 2;        // node within wave (0..15)
    const int c    = lane & 3;         // feature octet within panel (0..3)
    const int node = (bid / npan) * NPB + wave * 16 + g;
    const int fbase = p * 32 + c * 8;

    const ushort* hp = hpan + (size_t)p * N * 32 + c * 8;   // + r*32 per gather

    int beg = 0, end = 0;
    if (node < N) { beg = rowptr[node]; end = beg + cntp[node]; }

    float acc[8] = {};
    int e = beg;
    u32x4 pk4 = (u32x4){0u, 0u, 0u, 0u};
    if (e < end) pk4 = *(const u32x4*)&edges[e];
    while (__any(e < end)) {
        u32x4 cur = pk4;
        int e2 = e + 4;
        if (e2 < end) pk4 = *(const u32x4*)&edges[e2];   // prefetch next packet
        if (e < end) {
            #pragma unroll
            for (int j = 0; j < 4; ++j) {
                uint pk = cur[j];
                float nv = bits2f(pk & 0xffff0000u);
                int r = (int)(pk & 0xffffu);
                u32x4 hv = *(const u32x4*)(hp + (size_t)r * 32);
                #pragma unroll
                for (int q = 0; q < 4; ++q) {
                    acc[2 * q]     += nv * bits2f(hv[q] << 16);
                    acc[2 * q + 1] += nv * bits2f(hv[q] & 0xffff0000u);
                }
            }
        }
        e = e2;
    }

    if (node < N) {
        float di = dinv[node];
        float d2 = di * di;
        u32x4 hs = *(const u32x4*)(hp + (size_t)node * 32);
        f32x4 bv0 = *(const f32x4*)&bias[fbase];
        f32x4 bv1 = *(const f32x4*)&bias[fbase + 4];
        f32x4 v0, v1;
        #pragma unroll
        for (int q = 0; q < 4; ++q) {
            float r0 = acc[2 * q]     + d2 * bits2f(hs[q] << 16)
                     + ((q < 2) ? bv0[2 * q] : bv1[2 * q - 4]);
            float r1 = acc[2 * q + 1] + d2 * bits2f(hs[q] & 0xffff0000u)
                     + ((q < 2) ? bv0[2 * q + 1] : bv1[2 * q - 3]);
            if (RELU) { r0 = fmaxf(r0, 0.f); r1 = fmaxf(r1, 0.f); }
            if (q < 2) { v0[2 * q] = r0; v0[2 * q + 1] = r1; }
            else       { v1[2 * q - 4] = r0; v1[2 * q - 3] = r1; }
        }
        *(f32x4*)&out[(size_t)node * F + fbase]     = v0;
        *(f32x4*)&out[(size_t)node * F + fbase + 4] = v1;
    }
}

__global__ __launch_bounds__(256)
void k_aggr1(const int* __restrict__ rowptr, const int* __restrict__ cntp,
             const uint* __restrict__ edges, const ushort* __restrict__ hpan,
             const float* __restrict__ dinv, const float* __restrict__ bias,
             float* __restrict__ out, int F, int npan, int N) {
    aggr_body<true>(rowptr, cntp, edges, hpan, dinv, bias, out, F, npan, N);
}

__global__ __launch_bounds__(256)
void k_aggr2(const int* __restrict__ rowptr, const int* __restrict__ cntp,
             const uint* __restrict__ edges, const ushort* __restrict__ hpan,
             const float* __restrict__ dinv, const float* __restrict__ bias,
             float* __restrict__ out, int F, int npan, int N) {
    aggr_body<false>(rowptr, cntp, edges, hpan, dinv, bias, out, F, npan, N);
}

// ================= launcher =================

static inline char* bump(char*& p, size_t bytes) {
    char* r = p;
    p += (bytes + 255) & ~(size_t)255;
    return r;
}

extern "C" void kernel_launch(void* const* d_in, const int* in_sizes, int n_in,
                              void* d_out, int out_size, void* d_ws, size_t ws_size,
                              hipStream_t stream) {
    const float* x  = (const float*)d_in[0];
    const int*   ei = (const int*)d_in[1];
    const float* ew = (const float*)d_in[2];
    const float* W1 = (const float*)d_in[3];
    const float* b1 = (const float*)d_in[4];
    const float* W2 = (const float*)d_in[5];
    const float* b2 = (const float*)d_in[6];
    float* out = (float*)d_out;

    const int E    = in_sizes[2];
    const int H    = in_sizes[4];       // 256
    const int Fout = in_sizes[6];       // 128
    const int Fin  = in_sizes[3] / H;   // 256
    const int N    = in_sizes[0] / Fin; // 50000 (fits ushort)
    const int NB   = (N + 63) >> 6;     // buckets of 64 nodes (<= 1023)

    const int* row = ei;
    const int* col = ei + E;

    char* p = (char*)d_ws;
    float*  dinv   = (float*)bump(p, (size_t)N * 4);
    int*    cntp   = (int*)bump(p, (size_t)N * 4);
    int*    rowptr = (int*)bump(p, (size_t)N * 4);
    uint*   edgesP = (uint*)bump(p, ((size_t)E + 4 * N + 256) * 4);
    int*    counts = (int*)bump(p, (size_t)NBMAX * NBLK * 4);
    int*    btot   = (int*)bump(p, (size_t)NBMAX * 4);
    int*    bbase  = (int*)bump(p, (size_t)(NBMAX + 1) * 4);
    int*    btotP  = (int*)bump(p, (size_t)NBMAX * 4);
    int*    bbaseP = (int*)bump(p, (size_t)(NBMAX + 1) * 4);
    ushort* WT1h   = (ushort*)bump(p, (size_t)Fin * H * 2);
    ushort* WT1l   = (ushort*)bump(p, (size_t)Fin * H * 2);
    ushort* WT2h   = (ushort*)bump(p, (size_t)H * Fout * 2);
    ushort* WT2l   = (ushort*)bump(p, (size_t)H * Fout * 2);
    ushort* h1     = (ushort*)bump(p, (size_t)N * H * 2);     // panel-major bf16
    float*  a1     = (float*)bump(p, (size_t)N * H * 4);      // row-major fp32
    ushort* h2     = (ushort*)bump(p, (size_t)N * Fout * 2);  // panel-major bf16

    // recs overlays a1: consumed by binD_a/b before a1 is first written.
    ull* recs = (ull*)a1;

    const int sp1 = (Fin * H + 255) / 256;      // 256
    const int sp2 = (H * Fout + 255) / 256;     // 128
    const int gb1 = (H / 128) * ((N + 127) / 128);   // GEMM1 tiles (782)
    int T1 = gb1 < 280 ? gb1 : 280;
    int T2 = gb1 < 480 ? gb1 : 480;
    if (T2 < T1) T2 = T1;

    // stage A: edge histogram || weight split/transpose
    k_fusedA<<<NBLK + sp1 + sp2, 256, 0, stream>>>(col, counts, E, NB,
                                                   W1, WT1h, WT1l, Fin, H,
                                                   W2, WT2h, WT2l, Fout, sp1);
    k_scanB1<<<NB, 256, 0, stream>>>(counts, btot);
    k_scanB2<<<1, 256, 0, stream>>>(btot, bbase, NB);
    // stage B: bucket-sort || GEMM1 tiles [0,T1)
    k_fusedB1<<<NBLK + T1, 256, 0, stream>>>(row, col, ew, counts, bbase, recs, E, NB,
                                             x, WT1h, WT1l, h1, N, H, Fin, 0);
    // stage C: per-node counts/dinv || GEMM1 tiles [T1,T2)
    k_fusedB2<<<NB + (T2 - T1), 256, 0, stream>>>(recs, bbase, cntp, dinv, btotP, N, NB,
                                                  x, WT1h, WT1l, h1, N, H, Fin, T1);
    k_scanB2<<<1, 256, 0, stream>>>(btotP, bbaseP, NB);
    // stage D: CSR emission (packed bf16 norm) || GEMM1 tiles [T2,gb1)
    k_fusedB3<<<NB + (gb1 - T2), 256, 0, stream>>>(recs, bbase, bbaseP, cntp, dinv,
                                                   rowptr, edgesP, N, NB,
                                                   x, WT1h, WT1l, h1, N, H, Fin, T2);

    const int chunks = (N + NPB - 1) / NPB;

    // layer 1 aggregation
    k_aggr1<<<chunks * (H / 32), 256, 0, stream>>>(rowptr, cntp, edgesP, h1, dinv, b1, a1, H, H / 32, N);

    // layer 2
    k_gemm3<<<dim3(Fout / 128, (N + 127) / 128), 256, 0, stream>>>(a1, WT2h, WT2l, h2, N, Fout, H);
    k_aggr2<<<chunks * (Fout / 32), 256, 0, stream>>>(rowptr, cntp, edgesP, h2, dinv, b2, out, Fout, Fout / 32, N);
}